// Round 1
// baseline (1604.219 us; speedup 1.0000x reference)
//
#include <hip/hip_runtime.h>

#define LOG2E 1.44269504088896340736f

// 4 lanes cooperate on one batch row. Lane q computes output neurons
// [5q, 5q+5); all 20 activations are replicated in each lane's registers
// (compile-time indices only -> stays in VGPRs). Per layer:
//   - 25x global_load_dwordx4 of this lane's 5 weight rows (contiguous)
//   - 100 fmaf into 5 accumulators
//   - 5x sigmoid via exp2/rcp (weights folded: sigmoid(z)=1/(1+2^(-log2e*z)))
//   - 20x __shfl (ds_bpermute) to re-replicate h across the 4-lane group
__global__ __launch_bounds__(256, 1) void mann_fwd(
    const float* __restrict__ x,
    const float* __restrict__ W,
    const float* __restrict__ b,
    const float* __restrict__ Wout,
    const float* __restrict__ bout,
    float* __restrict__ out,
    int B, int L)
{
    const int tid = blockIdx.x * 256 + threadIdx.x;
    const int r = tid >> 2;          // batch row
    if (r >= B) return;
    const int lane = threadIdx.x & 63;
    const int q = lane & 3;          // which 5-neuron slice this lane owns
    const int base = lane & ~3;      // first lane of this row's 4-lane group

    float h[20];
    const float4* xv = reinterpret_cast<const float4*>(x + (size_t)r * 20);
#pragma unroll
    for (int c = 0; c < 5; ++c) {
        float4 v = xv[c];
        h[4*c+0] = v.x; h[4*c+1] = v.y; h[4*c+2] = v.z; h[4*c+3] = v.w;
    }

    for (int l = 0; l < L; ++l) {
        const float* wl = W + (size_t)l * 400 + q * 100;  // 5 contiguous rows
        const float* bl = b + (size_t)l * 20 + q * 5;
        float acc[5];
#pragma unroll
        for (int k = 0; k < 5; ++k) acc[k] = bl[k];
#pragma unroll
        for (int k = 0; k < 5; ++k) {
            const float4* wv = reinterpret_cast<const float4*>(wl + k * 20);
#pragma unroll
            for (int c = 0; c < 5; ++c) {
                const float4 wq = wv[c];
                acc[k] = fmaf(h[4*c+0], wq.x, acc[k]);
                acc[k] = fmaf(h[4*c+1], wq.y, acc[k]);
                acc[k] = fmaf(h[4*c+2], wq.z, acc[k]);
                acc[k] = fmaf(h[4*c+3], wq.w, acc[k]);
            }
        }
        float hn[5];
#pragma unroll
        for (int k = 0; k < 5; ++k) {
            float e = __builtin_amdgcn_exp2f(-LOG2E * acc[k]);
            hn[k] = __builtin_amdgcn_rcpf(1.0f + e);
        }
        // Re-replicate: h[5p+k] comes from lane (base+p)'s hn[k].
        // Destination indices are compile-time -> h stays in registers.
#pragma unroll
        for (int p = 0; p < 4; ++p) {
#pragma unroll
            for (int k = 0; k < 5; ++k) {
                h[5*p + k] = __shfl(hn[k], base + p, 64);
            }
        }
    }

    // Final Linear(20,1) + sigmoid: every lane has the full h; lane 0 of the
    // group computes and writes (cost is negligible: once per row).
    if (q == 0) {
        float z = bout[0];
#pragma unroll
        for (int i = 0; i < 20; ++i) z = fmaf(h[i], Wout[i], z);
        float e = __builtin_amdgcn_exp2f(-LOG2E * z);
        out[r] = __builtin_amdgcn_rcpf(1.0f + e);
    }
}

extern "C" void kernel_launch(void* const* d_in, const int* in_sizes, int n_in,
                              void* d_out, int out_size, void* d_ws, size_t ws_size,
                              hipStream_t stream) {
    const float* x    = (const float*)d_in[0];
    const float* W    = (const float*)d_in[1];
    const float* b    = (const float*)d_in[2];
    const float* Wout = (const float*)d_in[3];
    const float* bout = (const float*)d_in[4];
    float* out = (float*)d_out;

    const int B = in_sizes[0] / 20;    // 16384
    const int L = in_sizes[1] / 400;   // 1000

    const int threads = B * 4;         // 4 lanes per row
    const int block = 256;
    const int grid = (threads + block - 1) / block;
    mann_fwd<<<grid, block, 0, stream>>>(x, W, b, Wout, bout, out, B, L);
}

// Round 2
// 1592.829 us; speedup vs baseline: 1.0072x; 1.0072x over previous
//
#include <hip/hip_runtime.h>

#define LOG2E 1.44269504088896340736f

// DPP quad_perm broadcast: replicate lane (quad_base+P)'s value to all 4
// lanes of the quad. Pure VALU op (no LDS pipe), ~4 cyc latency.
template<int CTRL>
__device__ __forceinline__ float dpp_bcast(float v) {
    int i = __builtin_bit_cast(int, v);
    int r = __builtin_amdgcn_update_dpp(0, i, CTRL, 0xF, 0xF, true);
    return __builtin_bit_cast(float, r);
}

// 4 lanes per batch row. Lane q owns output neurons [5q, 5q+5).
// Per layer: 25 dwordx4 weight loads (double-buffered, prefetched one layer
// ahead into registers), 100 FMA, 5 sigmoid (exp2+rcp), 20 DPP broadcasts.
__global__ __launch_bounds__(256, 1) void mann_fwd(
    const float* __restrict__ x,
    const float* __restrict__ W,
    const float* __restrict__ b,
    const float* __restrict__ Wout,
    const float* __restrict__ bout,
    float* __restrict__ out,
    int B, int L)
{
    const int tid = blockIdx.x * 256 + threadIdx.x;
    const int r = tid >> 2;          // batch row
    if (r >= B) return;              // grid is exact; never taken
    const int q = threadIdx.x & 3;   // 5-neuron slice owned by this lane

    float h[20];
    const float4* xv = reinterpret_cast<const float4*>(x + (size_t)r * 20);
#pragma unroll
    for (int c = 0; c < 5; ++c) {
        float4 v = xv[c];
        h[4*c+0] = v.x; h[4*c+1] = v.y; h[4*c+2] = v.z; h[4*c+3] = v.w;
    }

    // Double-buffered per-layer weights/bias in registers (~210 VGPRs).
    float4 wA[25], wB[25];
    float  bA[5],  bB[5];

    auto loadw = [&](float4 (&wbuf)[25], float (&bbuf)[5], int l) {
        const float4* wv = reinterpret_cast<const float4*>(
            W + (size_t)l * 400 + q * 100);   // 5 contiguous rows, 16B aligned
#pragma unroll
        for (int c = 0; c < 25; ++c) wbuf[c] = wv[c];
        const float* bl = b + (size_t)l * 20 + q * 5;
#pragma unroll
        for (int k = 0; k < 5; ++k) bbuf[k] = bl[k];
    };

    auto compute = [&](const float4 (&wbuf)[25], const float (&bbuf)[5]) {
        float acc[5];
#pragma unroll
        for (int k = 0; k < 5; ++k) acc[k] = bbuf[k];
#pragma unroll
        for (int k = 0; k < 5; ++k) {
#pragma unroll
            for (int c = 0; c < 5; ++c) {
                const float4 w = wbuf[k*5 + c];
                acc[k] = fmaf(h[4*c+0], w.x, acc[k]);
                acc[k] = fmaf(h[4*c+1], w.y, acc[k]);
                acc[k] = fmaf(h[4*c+2], w.z, acc[k]);
                acc[k] = fmaf(h[4*c+3], w.w, acc[k]);
            }
        }
        float hn[5];
#pragma unroll
        for (int k = 0; k < 5; ++k) {
            float e = __builtin_amdgcn_exp2f(-LOG2E * acc[k]);
            hn[k] = __builtin_amdgcn_rcpf(1.0f + e);
        }
        // Re-replicate across the quad: h[5p+k] <- lane p's hn[k].
#pragma unroll
        for (int k = 0; k < 5; ++k) {
            h[ 0 + k] = dpp_bcast<0x00>(hn[k]);  // quad_perm [0,0,0,0]
            h[ 5 + k] = dpp_bcast<0x55>(hn[k]);  // quad_perm [1,1,1,1]
            h[10 + k] = dpp_bcast<0xAA>(hn[k]);  // quad_perm [2,2,2,2]
            h[15 + k] = dpp_bcast<0xFF>(hn[k]);  // quad_perm [3,3,3,3]
        }
    };

    loadw(wA, bA, 0);
    for (int l = 0; l < L; l += 2) {
        if (l + 1 < L) loadw(wB, bB, l + 1);   // prefetch next layer
        compute(wA, bA);
        if (l + 2 < L) loadw(wA, bA, l + 2);   // prefetch layer after
        if (l + 1 < L) compute(wB, bB);
    }

    // Final Linear(20,1) + sigmoid; one lane per row writes.
    if (q == 0) {
        float z = bout[0];
#pragma unroll
        for (int i = 0; i < 20; ++i) z = fmaf(h[i], Wout[i], z);
        float e = __builtin_amdgcn_exp2f(-LOG2E * z);
        out[r] = __builtin_amdgcn_rcpf(1.0f + e);
    }
}

extern "C" void kernel_launch(void* const* d_in, const int* in_sizes, int n_in,
                              void* d_out, int out_size, void* d_ws, size_t ws_size,
                              hipStream_t stream) {
    const float* x    = (const float*)d_in[0];
    const float* W    = (const float*)d_in[1];
    const float* b    = (const float*)d_in[2];
    const float* Wout = (const float*)d_in[3];
    const float* bout = (const float*)d_in[4];
    float* out = (float*)d_out;

    const int B = in_sizes[0] / 20;    // 16384
    const int L = in_sizes[1] / 400;   // 1000

    const int threads = B * 4;         // 4 lanes per row
    const int block = 256;
    const int grid = (threads + block - 1) / block;
    mann_fwd<<<grid, block, 0, stream>>>(x, W, b, Wout, bout, out, B, L);
}

// Round 3
// 1103.367 us; speedup vs baseline: 1.4539x; 1.4436x over previous
//
#include <hip/hip_runtime.h>

#define LOG2E 1.44269504088896340736f

constexpr int CL = 10;        // layers staged per chunk
constexpr int LSTRIDE = 420;  // floats per layer in LDS: 400 W + 20 b

// DPP quad_perm broadcast: replicate lane (quad_base+P)'s value across the
// quad. Pure VALU op, no LDS pipe.
template<int CTRL>
__device__ __forceinline__ float dpp_bcast(float v) {
    int i = __builtin_bit_cast(int, v);
    int r = __builtin_amdgcn_update_dpp(0, i, CTRL, 0xF, 0xF, true);
    return __builtin_bit_cast(float, r);
}

// 4 lanes per batch row; lane q owns output neurons [5q,5q+5).
// Weights double-buffered in LDS, staged with the async split:
//   stage_load (global->VGPR) at chunk top, stage_write (VGPR->LDS) at
//   chunk bottom -> ~4000 cyc of compute hides the global latency.
__global__ __launch_bounds__(256, 1) void mann_fwd(
    const float* __restrict__ x,
    const float* __restrict__ W,
    const float* __restrict__ b,
    const float* __restrict__ Wout,
    const float* __restrict__ bout,
    float* __restrict__ out,
    int B, int L)
{
    __shared__ float lds[2][CL * LSTRIDE];   // 2 * 16.8 KB = 33.6 KB

    const int tid = threadIdx.x;
    const int r = (blockIdx.x * 256 + tid) >> 2;   // batch row
    const int q = tid & 3;                          // neuron slice

    float h[20];
    const float4* xv = reinterpret_cast<const float4*>(x + (size_t)r * 20);
#pragma unroll
    for (int c = 0; c < 5; ++c) {
        float4 v = xv[c];
        h[4*c+0] = v.x; h[4*c+1] = v.y; h[4*c+2] = v.z; h[4*c+3] = v.w;
    }

    float4 wreg[4];   // in-flight staging registers (~17 float4 worth of work,
    float4 breg;      // CL*100=1000 W-float4 + CL*5=50 b-float4 per block)

    auto stage_load = [&](int c) {
        const float4* gw = reinterpret_cast<const float4*>(W + (size_t)c * CL * 400);
#pragma unroll
        for (int j = 0; j < 4; ++j) {
            int idx = j * 256 + tid;
            if (idx < CL * 100) wreg[j] = gw[idx];
        }
        if (tid < CL * 5)
            breg = reinterpret_cast<const float4*>(b + (size_t)c * CL * 20)[tid];
    };
    auto stage_write = [&](int bufi) {
        float* base = lds[bufi];
#pragma unroll
        for (int j = 0; j < 4; ++j) {
            int idx = j * 256 + tid;
            if (idx < CL * 100) {
                int lay = idx / 100, off = idx % 100;
                *reinterpret_cast<float4*>(base + lay * LSTRIDE + off * 4) = wreg[j];
            }
        }
        if (tid < CL * 5) {
            int lay = tid / 5, off = tid % 5;
            *reinterpret_cast<float4*>(base + lay * LSTRIDE + 400 + off * 4) = breg;
        }
    };

    stage_load(0);
    stage_write(0);
    __syncthreads();

    const int NC = L / CL;   // 100
    for (int c = 0; c < NC; ++c) {
        if (c + 1 < NC) stage_load(c + 1);          // issue early
        const float* lw = lds[c & 1];
#pragma unroll 2
        for (int l = 0; l < CL; ++l) {
            const float* wl = lw + l * LSTRIDE + q * 100;  // 5 rows, 16B aligned
            const float* bl = lw + l * LSTRIDE + 400 + q * 5;
            float acc[5];
#pragma unroll
            for (int k = 0; k < 5; ++k) acc[k] = bl[k];
#pragma unroll
            for (int k = 0; k < 5; ++k) {
#pragma unroll
                for (int cc = 0; cc < 5; ++cc) {
                    const float4 w = *reinterpret_cast<const float4*>(wl + k * 20 + cc * 4);
                    acc[k] = fmaf(h[4*cc+0], w.x, acc[k]);
                    acc[k] = fmaf(h[4*cc+1], w.y, acc[k]);
                    acc[k] = fmaf(h[4*cc+2], w.z, acc[k]);
                    acc[k] = fmaf(h[4*cc+3], w.w, acc[k]);
                }
            }
            float hn[5];
#pragma unroll
            for (int k = 0; k < 5; ++k) {
                float e = __builtin_amdgcn_exp2f(-LOG2E * acc[k]);
                hn[k] = __builtin_amdgcn_rcpf(1.0f + e);
            }
#pragma unroll
            for (int k = 0; k < 5; ++k) {
                h[ 0 + k] = dpp_bcast<0x00>(hn[k]);
                h[ 5 + k] = dpp_bcast<0x55>(hn[k]);
                h[10 + k] = dpp_bcast<0xAA>(hn[k]);
                h[15 + k] = dpp_bcast<0xFF>(hn[k]);
            }
        }
        if (c + 1 < NC) stage_write((c + 1) & 1);   // write late (loads long done)
        __syncthreads();
    }

    if (q == 0) {
        float z = bout[0];
#pragma unroll
        for (int i = 0; i < 20; ++i) z = fmaf(h[i], Wout[i], z);
        float e = __builtin_amdgcn_exp2f(-LOG2E * z);
        out[r] = __builtin_amdgcn_rcpf(1.0f + e);
    }
}

extern "C" void kernel_launch(void* const* d_in, const int* in_sizes, int n_in,
                              void* d_out, int out_size, void* d_ws, size_t ws_size,
                              hipStream_t stream) {
    const float* x    = (const float*)d_in[0];
    const float* W    = (const float*)d_in[1];
    const float* b    = (const float*)d_in[2];
    const float* Wout = (const float*)d_in[3];
    const float* bout = (const float*)d_in[4];
    float* out = (float*)d_out;

    const int B = in_sizes[0] / 20;    // 16384
    const int L = in_sizes[1] / 400;   // 1000

    const int threads = B * 4;         // 4 lanes per row
    const int block = 256;
    const int grid = (threads + block - 1) / block;  // 256 blocks = 1/CU
    mann_fwd<<<grid, block, 0, stream>>>(x, W, b, Wout, bout, out, B, L);
}

// Round 4
// 557.813 us; speedup vs baseline: 2.8759x; 1.9780x over previous
//
#include <hip/hip_runtime.h>

#define LOG2E 1.44269504088896340736f

constexpr int CL      = 10;          // layers per staged chunk
constexpr int LAYER_F = 432;         // floats per layer block in LDS: 400 W + 32 padded bias
constexpr int LAYER_B = LAYER_F * 4; // 1728 bytes
constexpr int CHUNK_F = CL * LAYER_F;
constexpr int CHUNK_B = CHUNK_F * 4; // 17280 bytes

// DPP quad_perm broadcast across the 4-lane group (pure VALU).
template<int CTRL>
__device__ __forceinline__ float dpp_bcast(float v) {
    int i = __builtin_bit_cast(int, v);
    int r = __builtin_amdgcn_update_dpp(0, i, CTRL, 0xF, 0xF, true);
    return __builtin_bit_cast(float, r);
}

// Per-layer weight fragment held in registers: 25 float4 of W + bias (4+1).
struct WBuf {
    float4 w[26];   // w[0..24] = W rows, w[25] = bias[0..3]
    float  b4;      // bias[4]
};

// Issue all 27 LDS reads for one layer as volatile asm (cannot be sunk or
// shrunk by the scheduler). wa = lane's W base (byte LDS addr), ba = lane's
// bias base. Reads land asynchronously; consumer waits lgkmcnt(0).
__device__ __forceinline__ void issue_reads(uint32_t wa, uint32_t ba, WBuf& d) {
#pragma unroll
    for (int i = 0; i < 25; ++i) {
        asm volatile("ds_read_b128 %0, %1 offset:%2"
                     : "=v"(d.w[i])
                     : "v"(wa), "n"((i / 5) * 80 + (i % 5) * 16));
    }
    asm volatile("ds_read_b128 %0, %1 offset:0" : "=v"(d.w[25]) : "v"(ba));
    asm volatile("ds_read_b32 %0, %1 offset:16" : "=v"(d.b4) : "v"(ba));
}

__device__ __forceinline__ void compute_layer(const WBuf& wb, float (&h)[20]) {
    float acc[5];
    acc[0] = wb.w[25].x; acc[1] = wb.w[25].y; acc[2] = wb.w[25].z;
    acc[3] = wb.w[25].w; acc[4] = wb.b4;
#pragma unroll
    for (int k = 0; k < 5; ++k) {
#pragma unroll
        for (int c = 0; c < 5; ++c) {
            const float4 w = wb.w[k * 5 + c];
            acc[k] = fmaf(h[4*c+0], w.x, acc[k]);
            acc[k] = fmaf(h[4*c+1], w.y, acc[k]);
            acc[k] = fmaf(h[4*c+2], w.z, acc[k]);
            acc[k] = fmaf(h[4*c+3], w.w, acc[k]);
        }
    }
    float hn[5];
#pragma unroll
    for (int k = 0; k < 5; ++k) {
        float e = __builtin_amdgcn_exp2f(-LOG2E * acc[k]);
        hn[k] = __builtin_amdgcn_rcpf(1.0f + e);
    }
#pragma unroll
    for (int k = 0; k < 5; ++k) {
        h[ 0 + k] = dpp_bcast<0x00>(hn[k]);
        h[ 5 + k] = dpp_bcast<0x55>(hn[k]);
        h[10 + k] = dpp_bcast<0xAA>(hn[k]);
        h[15 + k] = dpp_bcast<0xFF>(hn[k]);
    }
}

// 4 lanes per batch row; lane q owns output neurons [5q,5q+5).
__global__ __launch_bounds__(256, 1) void mann_fwd(
    const float* __restrict__ x,
    const float* __restrict__ W,
    const float* __restrict__ b,
    const float* __restrict__ Wout,
    const float* __restrict__ bout,
    float* __restrict__ out,
    int B, int L)
{
    __shared__ float lds[2][CHUNK_F];   // 2 x 17280 B

    const int tid = threadIdx.x;
    const int r = (blockIdx.x * 256 + tid) >> 2;
    const int q = tid & 3;

    float h[20];
    const float4* xv = reinterpret_cast<const float4*>(x + (size_t)r * 20);
#pragma unroll
    for (int c = 0; c < 5; ++c) {
        float4 v = xv[c];
        h[4*c+0] = v.x; h[4*c+1] = v.y; h[4*c+2] = v.z; h[4*c+3] = v.w;
    }

    // ---- global -> LDS staging (issue-early / write-late across a chunk) ----
    float4 wreg[4];   // CL*100 = 1000 float4 of W per chunk, 256 threads
    float  breg;      // CL*20  = 200 bias floats per chunk

    auto stage_load = [&](int c) {
        const float4* gw = reinterpret_cast<const float4*>(W + (size_t)c * CL * 400);
#pragma unroll
        for (int j = 0; j < 4; ++j) {
            int idx = j * 256 + tid;
            if (idx < CL * 100) wreg[j] = gw[idx];
        }
        if (tid < CL * 20) breg = b[(size_t)c * CL * 20 + tid];
    };
    auto stage_write = [&](int bufi) {
        float* base = lds[bufi];
#pragma unroll
        for (int j = 0; j < 4; ++j) {
            int idx = j * 256 + tid;
            if (idx < CL * 100) {
                int lay = idx / 100, off = idx % 100;
                *reinterpret_cast<float4*>(base + lay * LAYER_F + off * 4) = wreg[j];
            }
        }
        if (tid < CL * 20) {
            int lay = tid / 20, e = tid % 20;
            base[lay * LAYER_F + 400 + (e / 5) * 8 + (e % 5)] = breg;
        }
    };

    const uint32_t lbase = (uint32_t)(uintptr_t)&lds[0][0];

    stage_load(0);
    stage_write(0);
    __syncthreads();

    WBuf A, Bf;
    issue_reads(lbase + q * 400, lbase + 1600 + q * 32, A);   // layer 0

    const int NC = L / CL;
    for (int c = 0; c < NC; ++c) {
        if (c + 1 < NC) stage_load(c + 1);         // global loads, vmcnt domain
        const uint32_t cb = lbase + (c & 1) * CHUNK_B;
#pragma unroll
        for (int l = 0; l < CL; ++l) {
            WBuf& cur = (l & 1) ? Bf : A;
            WBuf& nxt = (l & 1) ? A : Bf;
            asm volatile("s_waitcnt lgkmcnt(0)");  // cur landed (issued 1 layer ago)
            __builtin_amdgcn_sched_barrier(0);     // don't hoist compute above wait
            if (l + 1 < CL)
                issue_reads(cb + (l + 1) * LAYER_B + q * 400,
                            cb + (l + 1) * LAYER_B + 1600 + q * 32, nxt);
            compute_layer(cur, h);                 // overlaps nxt's reads
        }
        if (c + 1 < NC) {
            stage_write((c + 1) & 1);              // write late (loads long done)
            __syncthreads();
            const uint32_t nb = lbase + ((c + 1) & 1) * CHUNK_B;
            issue_reads(nb + q * 400, nb + 1600 + q * 32, A);  // layer 0 of next
        }
    }

    if (q == 0) {
        float z = bout[0];
#pragma unroll
        for (int i = 0; i < 20; ++i) z = fmaf(h[i], Wout[i], z);
        float e = __builtin_amdgcn_exp2f(-LOG2E * z);
        out[r] = __builtin_amdgcn_rcpf(1.0f + e);
    }
}

extern "C" void kernel_launch(void* const* d_in, const int* in_sizes, int n_in,
                              void* d_out, int out_size, void* d_ws, size_t ws_size,
                              hipStream_t stream) {
    const float* x    = (const float*)d_in[0];
    const float* W    = (const float*)d_in[1];
    const float* b    = (const float*)d_in[2];
    const float* Wout = (const float*)d_in[3];
    const float* bout = (const float*)d_in[4];
    float* out = (float*)d_out;

    const int B = in_sizes[0] / 20;    // 16384
    const int L = in_sizes[1] / 400;   // 1000

    const int threads = B * 4;         // 4 lanes per row
    const int block = 256;
    const int grid = (threads + block - 1) / block;  // 256 blocks = 1/CU
    mann_fwd<<<grid, block, 0, stream>>>(x, W, b, Wout, bout, out, B, L);
}

// Round 5
// 273.340 us; speedup vs baseline: 5.8689x; 2.0407x over previous
//
#include <hip/hip_runtime.h>

#define LOG2E 1.44269504088896340736f

typedef __attribute__((ext_vector_type(8))) short short8;
typedef __attribute__((ext_vector_type(4))) float f32x4;

constexpr int CL       = 10;              // layers per staged chunk
constexpr int LAYER_BY = 2048;            // bytes/layer: 2 tiles x 64 lanes x 16B
constexpr int CHUNK_BY = CL * LAYER_BY;   // 20480
constexpr int CHUNK_V4 = CHUNK_BY / 16;   // 1280 float4
constexpr int V4_PER_T = CHUNK_V4 / 256;  // 5 per thread

// k-slot -> logical input position. Slot (h = lane>>4, e = 0..7):
//   e<4 -> pos 4h+e ; e>=4 -> pos 16+4h+(e-4)
// Chosen so the D-layout of layer l (lane holds rows {4h+j} u {16+4h+j},
// m89-verified col=lane&15,row=(lane>>4)*4+reg) feeds layer l+1's B fragment
// with ZERO cross-lane ops. Same mapping used for A (prepack) and B (runtime),
// so the HW's internal k order cancels. pos 20 carries bias (B supplies 1.0).
__device__ __forceinline__ int slot_pos(int h, int e) {
    return (e < 4) ? (4 * h + e) : (16 + 4 * h + (e - 4));
}

__device__ __forceinline__ unsigned short f32_to_bf16_rne(float f) {
    unsigned u = __builtin_bit_cast(unsigned, f);
    unsigned r = 0x7fffu + ((u >> 16) & 1u);
    return (unsigned short)((u + r) >> 16);
}

// One block per layer; 128 threads = 2 tiles x 64 lanes. Writes the bf16
// A-fragment stream: [layer][tile][lane] 16B units (linear, 2048B/layer).
__global__ void prepack(const float* __restrict__ W, const float* __restrict__ b,
                        unsigned int* __restrict__ wstream, int L)
{
    const int l    = blockIdx.x;
    const int t    = threadIdx.x >> 6;
    const int lane = threadIdx.x & 63;
    const int n    = t * 16 + (lane & 15);   // output-neuron position
    const int h    = lane >> 4;
    unsigned int words[4];
#pragma unroll
    for (int d = 0; d < 4; ++d) {
        unsigned short halves[2];
#pragma unroll
        for (int half = 0; half < 2; ++half) {
            int e   = d * 2 + half;
            int pos = slot_pos(h, e);
            float v = 0.f;
            if (n < 20) {
                if (pos < 20)       v = W[(size_t)l * 400 + n * 20 + pos];
                else if (pos == 20) v = b[(size_t)l * 20 + n];
            }
            halves[half] = f32_to_bf16_rne(v);
        }
        words[d] = (unsigned)halves[0] | ((unsigned)halves[1] << 16);
    }
    unsigned int* dst = wstream + ((size_t)l * LAYER_BY + t * 1024 + lane * 16) / 4;
    dst[0] = words[0]; dst[1] = words[1]; dst[2] = words[2]; dst[3] = words[3];
}

__device__ __forceinline__ unsigned cvt_pk_bf16(float lo, float hi) {
    unsigned r;
    asm("v_cvt_pk_bf16_f32 %0, %1, %2" : "=v"(r) : "v"(lo), "v"(hi));
    return r;
}

// Mask pad slots: h==0 keeps real positions 16..19; h==1 slot e=4 is pos 20
// -> constant 1.0 (bias multiplier); everything else in the upper half is pad.
__device__ __forceinline__ short8 finalize_B(unsigned p0, unsigned p1,
                                             unsigned p2, unsigned p3, int h) {
    if (h != 0) { p2 = (h == 1) ? 0x00003F80u : 0u; p3 = 0u; }
    union { unsigned u[4]; short8 s; } cv;
    cv.u[0] = p0; cv.u[1] = p1; cv.u[2] = p2; cv.u[3] = p3;
    return cv.s;
}

__device__ __forceinline__ float sigm(float z) {
    return __builtin_amdgcn_rcpf(1.f + __builtin_amdgcn_exp2f(-LOG2E * z));
}

__global__ __launch_bounds__(256, 1) void mann_mfma(
    const float* __restrict__ x, const unsigned int* __restrict__ wstream,
    const float* __restrict__ Wout, const float* __restrict__ bout,
    float* __restrict__ out, int B, int L)
{
    __shared__ unsigned char lds[2 * CHUNK_BY];   // 40 KiB double buffer

    const int tid  = threadIdx.x;
    const int lane = tid & 63;
    const int c16  = lane & 15;     // batch column within wave
    const int h    = lane >> 4;     // k-group / D-row group
    const int w    = (blockIdx.x * 256 + tid) >> 6;  // global wave id
    const int row  = w * 16 + c16;  // this lane's batch row

    // ---- first-layer B fragment from x (hi/lo packing straight from f32) ----
    const float4 xa = *reinterpret_cast<const float4*>(x + (size_t)row * 20 + 4 * h);
    const float4 xb = *reinterpret_cast<const float4*>(x + (size_t)row * 20 + 16);
    short8 Bf = finalize_B(cvt_pk_bf16(xa.x, xa.y), cvt_pk_bf16(xa.z, xa.w),
                           cvt_pk_bf16(xb.x, xb.y), cvt_pk_bf16(xb.z, xb.w), h);

    // ---- chunk staging: global->reg early, reg->LDS late (r4 pattern) ----
    float4 sreg[V4_PER_T];
    auto stage_load = [&](int c) {
        const float4* g = reinterpret_cast<const float4*>(wstream) + (size_t)c * CHUNK_V4;
#pragma unroll
        for (int j = 0; j < V4_PER_T; ++j) sreg[j] = g[j * 256 + tid];
    };
    auto stage_write = [&](int bufi) {
        float4* d = reinterpret_cast<float4*>(lds + bufi * CHUNK_BY);
#pragma unroll
        for (int j = 0; j < V4_PER_T; ++j) d[j * 256 + tid] = sreg[j];
    };

    const unsigned lbase = (unsigned)(uintptr_t)&lds[0];

    stage_load(0); stage_write(0); __syncthreads();

    // A-fragment double buffer, filled by volatile ds_read (can't be sunk).
    short8 a0A, a1A, a0B, a1B;
    auto issue_A = [&](unsigned addr, short8& t0, short8& t1) {
        asm volatile("ds_read_b128 %0, %1 offset:0"    : "=v"(t0) : "v"(addr));
        asm volatile("ds_read_b128 %0, %1 offset:1024" : "=v"(t1) : "v"(addr));
    };
    issue_A(lbase + lane * 16, a0A, a1A);

    const f32x4 zero = {0.f, 0.f, 0.f, 0.f};
    float s0, s1, s2, s3, s4, s5, s6, s7;

    const int NC = L / CL;
    for (int c = 0; c < NC; ++c) {
        if (c + 1 < NC) stage_load(c + 1);           // global prefetch (vmcnt)
        const unsigned cb = lbase + (c & 1) * CHUNK_BY + lane * 16;
#pragma unroll
        for (int ll = 0; ll < CL; ++ll) {
            const bool even = (ll & 1) == 0;
            short8& c0 = even ? a0A : a0B;
            short8& c1 = even ? a1A : a1B;
            short8& n0 = even ? a0B : a0A;
            short8& n1 = even ? a1B : a1A;
            asm volatile("s_waitcnt lgkmcnt(0)" ::: "memory");  // cur landed
            __builtin_amdgcn_sched_barrier(0);                  // rule #18
            if (ll + 1 < CL) issue_A(cb + (ll + 1) * LAYER_BY, n0, n1);
            // D[npos][batch]: tile0 rows 0-15 (neurons 0-15), tile1 rows 16-31
            // (neurons 16-19 + pad). Bias arrives via k-slot pos20 * 1.0.
            f32x4 acc0 = __builtin_amdgcn_mfma_f32_16x16x32_bf16(c0, Bf, zero, 0, 0, 0);
            f32x4 acc1 = __builtin_amdgcn_mfma_f32_16x16x32_bf16(c1, Bf, zero, 0, 0, 0);
            s0 = sigm(acc0[0]); s1 = sigm(acc0[1]); s2 = sigm(acc0[2]); s3 = sigm(acc0[3]);
            s4 = sigm(acc1[0]); s5 = sigm(acc1[1]); s6 = sigm(acc1[2]); s7 = sigm(acc1[3]);
            Bf = finalize_B(cvt_pk_bf16(s0, s1), cvt_pk_bf16(s2, s3),
                            cvt_pk_bf16(s4, s5), cvt_pk_bf16(s6, s7), h);
        }
        if (c + 1 < NC) {
            stage_write((c + 1) & 1);                // loads long since landed
            __syncthreads();
            issue_A(lbase + ((c + 1) & 1) * CHUNK_BY + lane * 16, a0A, a1A);
        }
    }

    // ---- epilogue: out[row] = sigmoid(sum_n h[n]*Wout[n] + bout) ----
    // Lane (h,c) holds neurons {4h+j} (s0-3, always real) and {16+4h+j}
    // (s4-7, real only for h==0).
    const float4 woa = *reinterpret_cast<const float4*>(Wout + 4 * h);
    const float4 wob = *reinterpret_cast<const float4*>(Wout + 16);
    float part = s0 * woa.x + s1 * woa.y + s2 * woa.z + s3 * woa.w;
    const float m = (h == 0) ? 1.f : 0.f;
    part += m * (s4 * wob.x + s5 * wob.y + s6 * wob.z + s7 * wob.w);
    part += __shfl_xor(part, 16, 64);
    part += __shfl_xor(part, 32, 64);
    if (h == 0) out[row] = sigm(part + bout[0]);
}

extern "C" void kernel_launch(void* const* d_in, const int* in_sizes, int n_in,
                              void* d_out, int out_size, void* d_ws, size_t ws_size,
                              hipStream_t stream) {
    const float* x    = (const float*)d_in[0];
    const float* W    = (const float*)d_in[1];
    const float* b    = (const float*)d_in[2];
    const float* Wout = (const float*)d_in[3];
    const float* bout = (const float*)d_in[4];
    float* out = (float*)d_out;

    const int B = in_sizes[0] / 20;    // 16384
    const int L = in_sizes[1] / 400;   // 1000

    unsigned int* wstream = (unsigned int*)d_ws;   // needs L*2048 B = 2.05 MB

    prepack<<<L, 128, 0, stream>>>(W, b, wstream, L);

    const int grid = B / 64;           // 16 rows/wave, 4 waves/block -> 256
    mann_mfma<<<grid, 256, 0, stream>>>(x, wstream, Wout, bout, out, B, L);
}